// Round 10
// baseline (996.634 us; speedup 1.0000x reference)
//
#include <hip/hip_runtime.h>

#define EPS 1e-5f

typedef __attribute__((ext_vector_type(8))) short bf16x8;
typedef __attribute__((ext_vector_type(4))) float f32x4;
typedef __attribute__((ext_vector_type(4))) unsigned short u16x4;

__device__ __forceinline__ unsigned short f2b(float f) {   // f32 -> bf16 RNE
    unsigned u = __float_as_uint(f);
    unsigned r = (u + 0x7fffu + ((u >> 16) & 1u)) >> 16;
    return (unsigned short)r;
}
__device__ __forceinline__ float b2f(unsigned short h) {   // bf16 -> f32 exact
    return __uint_as_float((unsigned)h << 16);
}

// ---------------- graph preprocessing ----------------

__global__ void k_cnt(const int* __restrict__ col, const float* __restrict__ w,
                      int* __restrict__ counts, float* __restrict__ deg, int E) {
    int e = blockIdx.x * blockDim.x + threadIdx.x;
    if (e < E) {
        int c = col[e];
        atomicAdd(&counts[c], 1);
        atomicAdd(&deg[c], w[e]);
    }
}

__global__ void k_dinv(const float* __restrict__ deg, float* __restrict__ dinv, int N) {
    int i = blockIdx.x * blockDim.x + threadIdx.x;
    if (i < N) dinv[i] = rsqrtf(deg[i] + 1.0f);
}

__global__ __launch_bounds__(1024) void k_scan(const int* __restrict__ counts,
                                               int* __restrict__ starts, int N) {
    __shared__ int part[1024];
    int tid = threadIdx.x;
    int chunk = (N + 1023) / 1024;
    int i0 = tid * chunk, i1 = min(N, i0 + chunk);
    int s = 0;
    for (int i = i0; i < i1; ++i) s += counts[i];
    part[tid] = s;
    __syncthreads();
    for (int d = 1; d < 1024; d <<= 1) {
        int v = (tid >= d) ? part[tid - d] : 0;
        __syncthreads();
        part[tid] += v;
        __syncthreads();
    }
    int excl = (tid == 0) ? 0 : part[tid - 1];
    for (int i = i0; i < i1; ++i) { starts[i] = excl; excl += counts[i]; }
}

__global__ void k_fill(const int* __restrict__ row, const int* __restrict__ col,
                       const float* __restrict__ w, const float* __restrict__ dinv,
                       const int* __restrict__ starts, int* __restrict__ cursor,
                       int* __restrict__ row_s, float* __restrict__ nrm_s, int E) {
    int e = blockIdx.x * blockDim.x + threadIdx.x;
    if (e >= E) return;
    int c = col[e];
    int r = row[e];
    int j = starts[c] + atomicAdd(&cursor[c], 1);
    row_s[j] = r;
    nrm_s[j] = dinv[r] * w[e] * dinv[c];
}

// ---------------- conversions / packing ----------------

// f32 -> bf16, 4 elems/thread
__global__ void k_cvt(const float* __restrict__ X, unsigned short* __restrict__ O, int n4) {
    int t = blockIdx.x * blockDim.x + threadIdx.x;
    if (t >= n4) return;
    float4 v = *(const float4*)(X + (size_t)t * 4);
    u16x4 o;
    o[0] = f2b(v.x); o[1] = f2b(v.y); o[2] = f2b(v.z); o[3] = f2b(v.w);
    *(u16x4*)(O + (size_t)t * 4) = o;
}

// pack W [K][M] f32 -> Wp [K/8][M][8] bf16 (MFMA B-fragment friendly)
__global__ void k_packW(const float* __restrict__ W, unsigned short* __restrict__ Wp,
                        int K, int M) {
    int t = blockIdx.x * blockDim.x + threadIdx.x;
    if (t >= K * M) return;
    int k = t / M, j = t - k * M;
    Wp[((size_t)(k >> 3) * M + j) * 8 + (k & 7)] = f2b(W[t]);
}

// ---------------- aggregation (CSR gather, bf16 in/out, f32 accum) ----------------
// OUT[i,c] = bf16( sum_j nrm_s[j]*X[row_s[j],c] + dinv[i]^2 * X[i,c] )
__global__ __launch_bounds__(256) void k_gatherb(
        const int* __restrict__ starts, const int* __restrict__ counts,
        const int* __restrict__ row_s, const float* __restrict__ nrm_s,
        const unsigned short* __restrict__ X, const float* __restrict__ dinv,
        unsigned short* __restrict__ OUT, int N, int k4shift)
{
    int t = blockIdx.x * blockDim.x + threadIdx.x;
    int K4 = 1 << k4shift;                 // K/4
    if (t >= (N << k4shift)) return;
    int i = t >> k4shift;
    int c4 = t & (K4 - 1);
    const u16x4* X4 = (const u16x4*)X;
    int s0 = starts[i], cnt = counts[i];
    float a0 = 0.f, a1 = 0.f, a2 = 0.f, a3 = 0.f;
    for (int j = s0; j < s0 + cnt; ++j) {
        float w = nrm_s[j];
        u16x4 h = X4[(size_t)row_s[j] * K4 + c4];
        a0 += w * b2f(h[0]); a1 += w * b2f(h[1]);
        a2 += w * b2f(h[2]); a3 += w * b2f(h[3]);
    }
    float di = dinv[i];
    float dd = di * di;
    u16x4 hs = X4[(size_t)i * K4 + c4];
    a0 += dd * b2f(hs[0]); a1 += dd * b2f(hs[1]);
    a2 += dd * b2f(hs[2]); a3 += dd * b2f(hs[3]);
    u16x4 o;
    o[0] = f2b(a0); o[1] = f2b(a1); o[2] = f2b(a2); o[3] = f2b(a3);
    ((u16x4*)OUT)[t] = o;
}

// ---------------- MFMA GEMM ----------------
// Y[f32] = maybe_relu(A[bf16 NxK] @ W + bias); optional fused BN col-sums.
// Wp packed [K/8][M][8]. Block: 256 thr = 4 waves; wave w: rows i0=blk*64+w*16;
// each wave covers up to 4 col-tiles of 16 (nct). No LDS.
// Fragment layouts (gfx950 16x16x32_bf16, guide-verified):
//   A: row=lane&15, k=(lane>>4)*8+e ; B: col=lane&15, k=(lane>>4)*8+e
//   D: col=lane&15, row=(lane>>4)*4+reg
__global__ __launch_bounds__(256) void k_gemm_mfma(
        const unsigned short* __restrict__ A, const unsigned short* __restrict__ Wp,
        const float* __restrict__ bias, float* __restrict__ Y,
        int N, int K, int M, int relu,
        float* __restrict__ sums, float* __restrict__ sumsq)
{
    int tid = threadIdx.x;
    int wv = tid >> 6;
    int l = tid & 63;
    int lr = l & 15;          // A-row / B-col / D-col within tile
    int lk = l >> 4;          // k-group (0..3)
    int i0 = blockIdx.x * 64 + wv * 16;
    int bcol = blockIdx.y * 64;
    int nct = (M - bcol) >> 4; if (nct > 4) nct = 4;

    f32x4 acc[4] = {};
    int gr = i0 + lr;
    bool rowOk = (gr < N);
    const unsigned short* arow = A + (size_t)gr * K + lk * 8;

    for (int k0 = 0; k0 < K; k0 += 32) {
        bf16x8 af = {};
        if (rowOk) af = *(const bf16x8*)(arow + k0);
        const unsigned short* wp = Wp + ((size_t)(k0 >> 3) + lk) * M * 8;
#pragma unroll
        for (int ct = 0; ct < 4; ++ct) {
            if (ct < nct) {
                bf16x8 bf = *(const bf16x8*)(wp + (size_t)(bcol + ct * 16 + lr) * 8);
                acc[ct] = __builtin_amdgcn_mfma_f32_16x16x32_bf16(af, bf, acc[ct], 0, 0, 0);
            }
        }
    }

#pragma unroll
    for (int ct = 0; ct < 4; ++ct) {
        if (ct >= nct) continue;
        int j = bcol + ct * 16 + lr;
        float bj = bias ? bias[j] : 0.0f;
        float s = 0.f, s2 = 0.f;
#pragma unroll
        for (int r = 0; r < 4; ++r) {
            int gi = i0 + lk * 4 + r;
            if (gi < N) {
                float v = acc[ct][r] + bj;
                if (relu) v = fmaxf(v, 0.f);
                Y[(size_t)gi * M + j] = v;
                s += v; s2 += v * v;
            }
        }
        if (sums) {
            s  += __shfl_xor(s, 16);  s2 += __shfl_xor(s2, 16);
            s  += __shfl_xor(s, 32);  s2 += __shfl_xor(s2, 32);
            if (lk == 0) {
                atomicAdd(&sums[j], s);
                atomicAdd(&sumsq[j], s2);
            }
        }
    }
}

// ---------------- BN: f32 in -> bf16 out ----------------

__global__ void k_bnb(const float* __restrict__ Y, const float* __restrict__ sums,
                      const float* __restrict__ sumsq, const float* __restrict__ g,
                      const float* __restrict__ be, unsigned short* __restrict__ OUT,
                      int N, int M, int reluAfter) {
    int t = blockIdx.x * blockDim.x + threadIdx.x;
    int total = (N * M) >> 2;
    if (t >= total) return;
    int f4 = t << 2;
    int i = f4 / M;
    int f = f4 - i * M;
    (void)i;
    float invN = 1.0f / 50000.0f;
    float4 y = *(const float4*)(Y + f4);
    u16x4 o;
#pragma unroll
    for (int j = 0; j < 4; ++j) {
        float mean = sums[f + j] * invN;
        float var = sumsq[f + j] * invN - mean * mean;
        float v = g[f + j] * (((const float*)&y)[j] - mean) * rsqrtf(var + EPS) + be[f + j];
        if (reluAfter) v = fmaxf(v, 0.f);
        o[j] = f2b(v);
    }
    *(u16x4*)(OUT + f4) = o;
}

// out[i] = b2 + sum_k T[i,k] * W2[k]   (T f32)
__global__ void k_fc2(const float* __restrict__ T, const float* __restrict__ W2,
                      const float* __restrict__ b2, float* __restrict__ out,
                      int N, int K) {
    int i = blockIdx.x * blockDim.x + threadIdx.x;
    if (i >= N) return;
    const float* tr = T + (size_t)i * K;
    float acc = b2[0];
#pragma unroll 4
    for (int k = 0; k < K; ++k) acc += tr[k] * W2[k];
    out[i] = acc;
}

// ---------------- host ----------------

static inline size_t align256(size_t x) { return (x + 255) & ~(size_t)255; }

extern "C" void kernel_launch(void* const* d_in, const int* in_sizes, int n_in,
                              void* d_out, int out_size, void* d_ws, size_t ws_size,
                              hipStream_t stream) {
    const int F_IN = 32;
    const int N = in_sizes[0] / F_IN;   // 50000
    const int E = in_sizes[2];          // 400000

    const float* x  = (const float*)d_in[0];
    const int*   ei = (const int*)d_in[1];
    const float* ea = (const float*)d_in[2];
    const int* row = ei;
    const int* col = ei + E;

    const float* W[5]; const float* b[5]; const float* g[5]; const float* be[5];
    for (int i = 0; i < 5; ++i) {
        W[i]  = (const float*)d_in[3 + 4 * i + 0];
        b[i]  = (const float*)d_in[3 + 4 * i + 1];
        g[i]  = (const float*)d_in[3 + 4 * i + 2];
        be[i] = (const float*)d_in[3 + 4 * i + 3];
    }
    const float* fcW1 = (const float*)d_in[23];
    const float* fcb1 = (const float*)d_in[24];
    const float* fcW2 = (const float*)d_in[25];
    const float* fcb2 = (const float*)d_in[26];

    // workspace layout
    char* ws = (char*)d_ws;
    size_t off = 0;
    unsigned short* XB = (unsigned short*)(ws + off); off += align256((size_t)N * 256 * 2); // bf16 activations
    unsigned short* CB = (unsigned short*)(ws + off); off += align256((size_t)N * 128 * 2); // bf16 gathered
    float* Yf   = (float*)(ws + off); off += align256((size_t)N * 256 * 4);                 // f32 GEMM out
    float* deg  = (float*)(ws + off); off += align256((size_t)N * 4);
    float* dinv = (float*)(ws + off); off += align256((size_t)N * 4);
    int* counts = (int*)(ws + off); off += align256((size_t)N * 4);
    int* starts = (int*)(ws + off); off += align256((size_t)N * 4);
    int* cursor = (int*)(ws + off); off += align256((size_t)N * 4);
    int* row_s  = (int*)(ws + off); off += align256((size_t)E * 4);
    float* nrm_s = (float*)(ws + off); off += align256((size_t)E * 4);
    float* sums  = (float*)(ws + off); off += align256(512 * 4);   // sums(256) + sumsq(256) contiguous
    float* sumsq = sums + 256;
    // packed bf16 weights
    const int KW[6] = {32, 32, 64, 128, 128, 256};
    const int MW[6] = {32, 64, 128, 128, 256, 128};
    unsigned short* Wp[6];
    for (int i = 0; i < 6; ++i) { Wp[i] = (unsigned short*)(ws + off); off += align256((size_t)KW[i] * MW[i] * 2); }
    (void)ws_size;

    const int BS = 256;
    auto grid1 = [&](long long total) { return (int)((total + BS - 1) / BS); };

    // --- CSR build ---
    hipMemsetAsync(deg, 0, (size_t)N * 4, stream);
    hipMemsetAsync(counts, 0, (size_t)N * 4, stream);
    hipMemsetAsync(cursor, 0, (size_t)N * 4, stream);
    k_cnt<<<grid1(E), BS, 0, stream>>>(col, ea, counts, deg, E);
    k_dinv<<<grid1(N), BS, 0, stream>>>(deg, dinv, N);
    k_scan<<<1, 1024, 0, stream>>>(counts, starts, N);
    k_fill<<<grid1(E), BS, 0, stream>>>(row, col, ea, dinv, starts, cursor, row_s, nrm_s, E);

    // --- input + weight conversion to bf16 ---
    k_cvt<<<grid1((long long)N * F_IN / 4), BS, 0, stream>>>(x, XB, N * F_IN / 4);
    const float* Wsrc[6] = {W[0], W[1], W[2], W[3], W[4], fcW1};
    for (int i = 0; i < 6; ++i)
        k_packW<<<grid1((long long)KW[i] * MW[i]), BS, 0, stream>>>(Wsrc[i], Wp[i], KW[i], MW[i]);

    auto gemm = [&](const unsigned short* Ab, int l, const float* bias, float* Y,
                    int relu, float* s1, float* s2) {
        dim3 grid((N + 63) / 64, (MW[l] + 63) / 64);
        k_gemm_mfma<<<grid, 256, 0, stream>>>(Ab, Wp[l], bias, Y, N, KW[l], MW[l], relu, s1, s2);
    };

    // --- GCN layer: gatherb(XB)->CB ; mfma-gemm(+stats) -> Yf ; bn -> XB(bf16) ---
    auto layer = [&](int l, int reluBefore, int reluAfter) {
        int K = KW[l], M = MW[l];
        int k4shift = (K == 32) ? 3 : (K == 64) ? 4 : 5;
        k_gatherb<<<grid1((long long)N << k4shift), BS, 0, stream>>>(
            starts, counts, row_s, nrm_s, XB, dinv, CB, N, k4shift);
        hipMemsetAsync(sums, 0, 512 * 4, stream);
        gemm(CB, l, b[l], Yf, reluBefore, sums, sumsq);
        k_bnb<<<grid1((long long)N * M / 4), BS, 0, stream>>>(
            Yf, sums, sumsq, g[l], be[l], XB, N, M, reluAfter);
    };

    layer(0, 1, 0);   // 32 -> 32
    layer(1, 1, 0);   // 32 -> 64
    layer(2, 1, 0);   // 64 -> 128
    layer(3, 0, 1);   // 128 -> 128
    layer(4, 0, 1);   // 128 -> 256

    // FC1: XB(bf16 Nx256) @ fcW1 + b, ReLU -> Yf (f32 Nx128)
    gemm(XB, 5, fcb1, Yf, 1, nullptr, nullptr);
    // FC2
    k_fc2<<<grid1(N), BS, 0, stream>>>(Yf, fcW2, fcb2, (float*)d_out, N, 128);
}

// Round 11
// 981.103 us; speedup vs baseline: 1.0158x; 1.0158x over previous
//
#include <hip/hip_runtime.h>

#define EPS 1e-5f

typedef __attribute__((ext_vector_type(8))) short bf16x8;
typedef __attribute__((ext_vector_type(4))) float f32x4;
typedef __attribute__((ext_vector_type(4))) unsigned short u16x4;

__device__ __forceinline__ unsigned short f2b(float f) {   // f32 -> bf16 RNE
    unsigned u = __float_as_uint(f);
    unsigned r = (u + 0x7fffu + ((u >> 16) & 1u)) >> 16;
    return (unsigned short)r;
}
__device__ __forceinline__ float b2f(unsigned short h) {   // bf16 -> f32 exact
    return __uint_as_float((unsigned)h << 16);
}

// ---------------- graph preprocessing ----------------

__global__ void k_cnt(const int* __restrict__ col, const float* __restrict__ w,
                      int* __restrict__ counts, float* __restrict__ deg, int E) {
    int e = blockIdx.x * blockDim.x + threadIdx.x;
    if (e < E) {
        int c = col[e];
        atomicAdd(&counts[c], 1);
        atomicAdd(&deg[c], w[e]);
    }
}

__global__ void k_dinv(const float* __restrict__ deg, float* __restrict__ dinv, int N) {
    int i = blockIdx.x * blockDim.x + threadIdx.x;
    if (i < N) dinv[i] = rsqrtf(deg[i] + 1.0f);
}

__global__ __launch_bounds__(1024) void k_scan(const int* __restrict__ counts,
                                               int* __restrict__ starts, int N) {
    __shared__ int part[1024];
    int tid = threadIdx.x;
    int chunk = (N + 1023) / 1024;
    int i0 = tid * chunk, i1 = min(N, i0 + chunk);
    int s = 0;
    for (int i = i0; i < i1; ++i) s += counts[i];
    part[tid] = s;
    __syncthreads();
    for (int d = 1; d < 1024; d <<= 1) {
        int v = (tid >= d) ? part[tid - d] : 0;
        __syncthreads();
        part[tid] += v;
        __syncthreads();
    }
    int excl = (tid == 0) ? 0 : part[tid - 1];
    for (int i = i0; i < i1; ++i) { starts[i] = excl; excl += counts[i]; }
}

__global__ void k_fill(const int* __restrict__ row, const int* __restrict__ col,
                       const float* __restrict__ w, const float* __restrict__ dinv,
                       const int* __restrict__ starts, int* __restrict__ cursor,
                       int* __restrict__ row_s, float* __restrict__ nrm_s, int E) {
    int e = blockIdx.x * blockDim.x + threadIdx.x;
    if (e >= E) return;
    int c = col[e];
    int r = row[e];
    int j = starts[c] + atomicAdd(&cursor[c], 1);
    row_s[j] = r;
    nrm_s[j] = dinv[r] * w[e] * dinv[c];
}

// ---------------- weight pack: W [K][M] f32 -> Wp [M][K] bf16 (transposed) ----------------
__global__ void k_packWT(const float* __restrict__ W, unsigned short* __restrict__ Wp,
                         int K, int M) {
    int t = blockIdx.x * blockDim.x + threadIdx.x;
    if (t >= K * M) return;
    int k = t / M, j = t - k * M;
    Wp[(size_t)j * K + k] = f2b(W[t]);
}

// ---------------- aggregation (CSR gather, f32 in, bf16 out) ----------------
// OUT[i,c] = bf16( sum_j nrm_s[j]*X[row_s[j],c] + dinv[i]^2 * X[i,c] )
__global__ __launch_bounds__(256) void k_gather4b(
        const int* __restrict__ starts, const int* __restrict__ counts,
        const int* __restrict__ row_s, const float* __restrict__ nrm_s,
        const float* __restrict__ X, const float* __restrict__ dinv,
        unsigned short* __restrict__ OUT, int N, int k4shift)
{
    int t = blockIdx.x * blockDim.x + threadIdx.x;
    int K4 = 1 << k4shift;                 // K/4
    if (t >= (N << k4shift)) return;
    int i = t >> k4shift;
    int c4 = t & (K4 - 1);
    const float4* X4 = (const float4*)X;
    int s0 = starts[i], cnt = counts[i];
    float a0 = 0.f, a1 = 0.f, a2 = 0.f, a3 = 0.f;
    for (int j = s0; j < s0 + cnt; ++j) {
        float w = nrm_s[j];
        float4 h = X4[(size_t)row_s[j] * K4 + c4];
        a0 += w * h.x; a1 += w * h.y; a2 += w * h.z; a3 += w * h.w;
    }
    float di = dinv[i];
    float dd = di * di;
    float4 hs = X4[(size_t)i * K4 + c4];
    a0 += dd * hs.x; a1 += dd * hs.y; a2 += dd * hs.z; a3 += dd * hs.w;
    u16x4 o;
    o[0] = f2b(a0); o[1] = f2b(a1); o[2] = f2b(a2); o[3] = f2b(a3);
    ((u16x4*)OUT)[t] = o;
}

// ---------------- MFMA GEMM with LDS staging ----------------
// Y[f32] = maybe_relu(A[bf16 NxK] @ W + bias); optional fused BN col-sums.
// Wp is W^T [M][K] bf16. Block 256thr=4 waves, BM=64, BN=64(tiles of 16), BK=32.
// Wave wv: rows wv*16..+16; cols: 4 tiles of 16. LDS padded stride 40 (~2-way, free).
// Fragments (gfx950 16x16x32_bf16): A row=lane&15,k=(lane>>4)*8+e ;
//   B col=lane&15,k=(lane>>4)*8+e ; D col=lane&15,row=(lane>>4)*4+reg.
__global__ __launch_bounds__(256) void k_gemm_mfma(
        const unsigned short* __restrict__ A, const unsigned short* __restrict__ Wp,
        const float* __restrict__ bias, float* __restrict__ Y,
        int N, int K, int M, int relu,
        float* __restrict__ sums, float* __restrict__ sumsq)
{
    __shared__ unsigned short As[64][40];
    __shared__ unsigned short Bs[64][40];

    int tid = threadIdx.x;
    int wv = tid >> 6;
    int l = tid & 63;
    int lr = l & 15;
    int lk = l >> 4;
    int brow = blockIdx.x * 64;
    int bcol = blockIdx.y * 64;
    int nct = (M - bcol) >> 4; if (nct > 4) nct = 4;

    int sr = tid >> 2;             // staging row 0..63
    int sc = (tid & 3) * 8;        // staging col {0,8,16,24}
    int gr_s = brow + sr;
    int gj_s = bcol + sr;

    f32x4 acc[4] = {};

    for (int k0 = 0; k0 < K; k0 += 32) {
        bf16x8 va = {};
        if (gr_s < N) va = *(const bf16x8*)(A + (size_t)gr_s * K + k0 + sc);
        *(bf16x8*)&As[sr][sc] = va;
        bf16x8 vb = {};
        if (gj_s < M) vb = *(const bf16x8*)(Wp + (size_t)gj_s * K + k0 + sc);
        *(bf16x8*)&Bs[sr][sc] = vb;
        __syncthreads();

        bf16x8 af = *(const bf16x8*)&As[wv * 16 + lr][lk * 8];
#pragma unroll
        for (int ct = 0; ct < 4; ++ct) {
            if (ct < nct) {
                bf16x8 bf = *(const bf16x8*)&Bs[ct * 16 + lr][lk * 8];
                acc[ct] = __builtin_amdgcn_mfma_f32_16x16x32_bf16(af, bf, acc[ct], 0, 0, 0);
            }
        }
        __syncthreads();
    }

    int i0 = brow + wv * 16;
#pragma unroll
    for (int ct = 0; ct < 4; ++ct) {
        if (ct >= nct) continue;
        int j = bcol + ct * 16 + lr;
        float bj = bias ? bias[j] : 0.0f;
        float s = 0.f, s2 = 0.f;
#pragma unroll
        for (int r = 0; r < 4; ++r) {
            int gi = i0 + lk * 4 + r;
            if (gi < N) {
                float v = acc[ct][r] + bj;
                if (relu) v = fmaxf(v, 0.f);
                Y[(size_t)gi * M + j] = v;
                s += v; s2 += v * v;
            }
        }
        if (sums) {
            s  += __shfl_xor(s, 16);  s2 += __shfl_xor(s2, 16);
            s  += __shfl_xor(s, 32);  s2 += __shfl_xor(s2, 32);
            if (lk == 0) {
                atomicAdd(&sums[j], s);
                atomicAdd(&sumsq[j], s2);
            }
        }
    }
}

// ---------------- BN: f32 in -> f32 XF (optional) + bf16 XB ----------------

__global__ void k_bnb(const float* __restrict__ Y, const float* __restrict__ sums,
                      const float* __restrict__ sumsq, const float* __restrict__ g,
                      const float* __restrict__ be, float* __restrict__ OF,
                      unsigned short* __restrict__ OB,
                      int N, int M, int reluAfter, int writeF) {
    int t = blockIdx.x * blockDim.x + threadIdx.x;
    int total = (N * M) >> 2;
    if (t >= total) return;
    int f4 = t << 2;
    int i = f4 / M;
    int f = f4 - i * M;
    (void)i;
    float invN = 1.0f / 50000.0f;
    float4 y = *(const float4*)(Y + f4);
    float4 vf;
    u16x4 ob;
#pragma unroll
    for (int j = 0; j < 4; ++j) {
        float mean = sums[f + j] * invN;
        float var = sumsq[f + j] * invN - mean * mean;
        float v = g[f + j] * (((const float*)&y)[j] - mean) * rsqrtf(var + EPS) + be[f + j];
        if (reluAfter) v = fmaxf(v, 0.f);
        ((float*)&vf)[j] = v;
        ob[j] = f2b(v);
    }
    if (writeF) *(float4*)(OF + f4) = vf;
    *(u16x4*)(OB + f4) = ob;
}

// out[i] = b2 + sum_k T[i,k] * W2[k]   (T f32)
__global__ void k_fc2(const float* __restrict__ T, const float* __restrict__ W2,
                      const float* __restrict__ b2, float* __restrict__ out,
                      int N, int K) {
    int i = blockIdx.x * blockDim.x + threadIdx.x;
    if (i >= N) return;
    const float* tr = T + (size_t)i * K;
    float acc = b2[0];
#pragma unroll 4
    for (int k = 0; k < K; ++k) acc += tr[k] * W2[k];
    out[i] = acc;
}

// ---------------- host ----------------

static inline size_t align256(size_t x) { return (x + 255) & ~(size_t)255; }

extern "C" void kernel_launch(void* const* d_in, const int* in_sizes, int n_in,
                              void* d_out, int out_size, void* d_ws, size_t ws_size,
                              hipStream_t stream) {
    const int F_IN = 32;
    const int N = in_sizes[0] / F_IN;   // 50000
    const int E = in_sizes[2];          // 400000

    const float* x  = (const float*)d_in[0];
    const int*   ei = (const int*)d_in[1];
    const float* ea = (const float*)d_in[2];
    const int* row = ei;
    const int* col = ei + E;

    const float* W[5]; const float* b[5]; const float* g[5]; const float* be[5];
    for (int i = 0; i < 5; ++i) {
        W[i]  = (const float*)d_in[3 + 4 * i + 0];
        b[i]  = (const float*)d_in[3 + 4 * i + 1];
        g[i]  = (const float*)d_in[3 + 4 * i + 2];
        be[i] = (const float*)d_in[3 + 4 * i + 3];
    }
    const float* fcW1 = (const float*)d_in[23];
    const float* fcb1 = (const float*)d_in[24];
    const float* fcW2 = (const float*)d_in[25];
    const float* fcb2 = (const float*)d_in[26];

    // workspace layout
    char* ws = (char*)d_ws;
    size_t off = 0;
    float* XF = (float*)(ws + off); off += align256((size_t)N * 128 * 4);           // f32 BN out (layers 1-4, width<=128)
    unsigned short* XB = (unsigned short*)(ws + off); off += align256((size_t)N * 256 * 2); // bf16 BN out (FC1 input)
    unsigned short* CB = (unsigned short*)(ws + off); off += align256((size_t)N * 128 * 2); // bf16 gathered (GEMM A)
    float* Yf   = (float*)(ws + off); off += align256((size_t)N * 256 * 4);         // f32 GEMM out
    float* deg  = (float*)(ws + off); off += align256((size_t)N * 4);
    float* dinv = (float*)(ws + off); off += align256((size_t)N * 4);
    int* counts = (int*)(ws + off); off += align256((size_t)N * 4);
    int* starts = (int*)(ws + off); off += align256((size_t)N * 4);
    int* cursor = (int*)(ws + off); off += align256((size_t)N * 4);
    int* row_s  = (int*)(ws + off); off += align256((size_t)E * 4);
    float* nrm_s = (float*)(ws + off); off += align256((size_t)E * 4);
    float* sums  = (float*)(ws + off); off += align256(512 * 4);
    float* sumsq = sums + 256;
    const int KW[6] = {32, 32, 64, 128, 128, 256};
    const int MW[6] = {32, 64, 128, 128, 256, 128};
    unsigned short* Wp[6];
    for (int i = 0; i < 6; ++i) { Wp[i] = (unsigned short*)(ws + off); off += align256((size_t)KW[i] * MW[i] * 2); }
    (void)ws_size;

    const int BS = 256;
    auto grid1 = [&](long long total) { return (int)((total + BS - 1) / BS); };

    // --- CSR build ---
    hipMemsetAsync(deg, 0, (size_t)N * 4, stream);
    hipMemsetAsync(counts, 0, (size_t)N * 4, stream);
    hipMemsetAsync(cursor, 0, (size_t)N * 4, stream);
    k_cnt<<<grid1(E), BS, 0, stream>>>(col, ea, counts, deg, E);
    k_dinv<<<grid1(N), BS, 0, stream>>>(deg, dinv, N);
    k_scan<<<1, 1024, 0, stream>>>(counts, starts, N);
    k_fill<<<grid1(E), BS, 0, stream>>>(row, col, ea, dinv, starts, cursor, row_s, nrm_s, E);

    // --- weight packing (transpose + bf16) ---
    const float* Wsrc[6] = {W[0], W[1], W[2], W[3], W[4], fcW1};
    for (int i = 0; i < 6; ++i)
        k_packWT<<<grid1((long long)KW[i] * MW[i]), BS, 0, stream>>>(Wsrc[i], Wp[i], KW[i], MW[i]);

    auto gemm = [&](const unsigned short* Ab, int l, const float* bias, float* Y,
                    int relu, float* s1, float* s2) {
        dim3 grid((N + 63) / 64, (MW[l] + 63) / 64);
        k_gemm_mfma<<<grid, 256, 0, stream>>>(Ab, Wp[l], bias, Y, N, KW[l], MW[l], relu, s1, s2);
    };

    // --- GCN layer: gather(f32 in)->CB(bf16) ; mfma-gemm(+stats)->Yf ; bn->XF/XB ---
    auto layer = [&](const float* Xin, int l, int reluBefore, int reluAfter) {
        int K = KW[l], M = MW[l];
        int k4shift = (K == 32) ? 3 : (K == 64) ? 4 : 5;
        k_gather4b<<<grid1((long long)N << k4shift), BS, 0, stream>>>(
            starts, counts, row_s, nrm_s, Xin, dinv, CB, N, k4shift);
        hipMemsetAsync(sums, 0, 512 * 4, stream);
        gemm(CB, l, b[l], Yf, reluBefore, sums, sumsq);
        k_bnb<<<grid1((long long)N * M / 4), BS, 0, stream>>>(
            Yf, sums, sumsq, g[l], be[l], XF, XB, N, M, reluAfter, M <= 128 ? 1 : 0);
    };

    layer(x,  0, 1, 0);   // 32 -> 32
    layer(XF, 1, 1, 0);   // 32 -> 64
    layer(XF, 2, 1, 0);   // 64 -> 128
    layer(XF, 3, 0, 1);   // 128 -> 128
    layer(XF, 4, 0, 1);   // 128 -> 256 (bf16 only)

    // FC1: XB(bf16 Nx256) @ fcW1 + b, ReLU -> Yf (f32 Nx128)
    gemm(XB, 5, fcb1, Yf, 1, nullptr, nullptr);
    // FC2
    k_fc2<<<grid1(N), BS, 0, stream>>>(Yf, fcW2, fcb2, (float*)d_out, N, 128);
}

// Round 12
// 757.901 us; speedup vs baseline: 1.3150x; 1.2945x over previous
//
#include <hip/hip_runtime.h>

#define EPS 1e-5f

typedef __attribute__((ext_vector_type(8))) short bf16x8;
typedef __attribute__((ext_vector_type(4))) float f32x4;
typedef __attribute__((ext_vector_type(4))) unsigned short u16x4;

__device__ __forceinline__ unsigned short f2b(float f) {   // f32 -> bf16 RNE
    unsigned u = __float_as_uint(f);
    unsigned r = (u + 0x7fffu + ((u >> 16) & 1u)) >> 16;
    return (unsigned short)r;
}
__device__ __forceinline__ float b2f(unsigned short h) {   // bf16 -> f32 exact
    return __uint_as_float((unsigned)h << 16);
}

// ---------------- graph preprocessing ----------------

__global__ void k_cnt(const int* __restrict__ col, const float* __restrict__ w,
                      int* __restrict__ counts, float* __restrict__ deg, int E) {
    int e = blockIdx.x * blockDim.x + threadIdx.x;
    if (e < E) {
        int c = col[e];
        atomicAdd(&counts[c], 1);
        atomicAdd(&deg[c], w[e]);
    }
}

__global__ void k_dinv(const float* __restrict__ deg, float* __restrict__ dinv, int N) {
    int i = blockIdx.x * blockDim.x + threadIdx.x;
    if (i < N) dinv[i] = rsqrtf(deg[i] + 1.0f);
}

__global__ __launch_bounds__(1024) void k_scan(const int* __restrict__ counts,
                                               int* __restrict__ starts, int N) {
    __shared__ int part[1024];
    int tid = threadIdx.x;
    int chunk = (N + 1023) / 1024;
    int i0 = tid * chunk, i1 = min(N, i0 + chunk);
    int s = 0;
    for (int i = i0; i < i1; ++i) s += counts[i];
    part[tid] = s;
    __syncthreads();
    for (int d = 1; d < 1024; d <<= 1) {
        int v = (tid >= d) ? part[tid - d] : 0;
        __syncthreads();
        part[tid] += v;
        __syncthreads();
    }
    int excl = (tid == 0) ? 0 : part[tid - 1];
    for (int i = i0; i < i1; ++i) { starts[i] = excl; excl += counts[i]; }
}

__global__ void k_fill(const int* __restrict__ row, const int* __restrict__ col,
                       const float* __restrict__ w, const float* __restrict__ dinv,
                       const int* __restrict__ starts, int* __restrict__ cursor,
                       int* __restrict__ row_s, float* __restrict__ nrm_s, int E) {
    int e = blockIdx.x * blockDim.x + threadIdx.x;
    if (e >= E) return;
    int c = col[e];
    int r = row[e];
    int j = starts[c] + atomicAdd(&cursor[c], 1);
    row_s[j] = r;
    nrm_s[j] = dinv[r] * w[e] * dinv[c];
}

// ---------------- weight pack: W [K][M] f32 -> Wp [M][K] bf16 (transposed) ----------------
__global__ void k_packWT(const float* __restrict__ W, unsigned short* __restrict__ Wp,
                         int K, int M) {
    int t = blockIdx.x * blockDim.x + threadIdx.x;
    if (t >= K * M) return;
    int k = t / M, j = t - k * M;
    Wp[(size_t)j * K + k] = f2b(W[t]);
}

// ---------------- aggregation (CSR gather, f32 in, bf16 out) ----------------
// OUT[i,c] = bf16( sum_j nrm_s[j]*X[row_s[j],c] + dinv[i]^2 * X[i,c] )
__global__ __launch_bounds__(256) void k_gather4b(
        const int* __restrict__ starts, const int* __restrict__ counts,
        const int* __restrict__ row_s, const float* __restrict__ nrm_s,
        const float* __restrict__ X, const float* __restrict__ dinv,
        unsigned short* __restrict__ OUT, int N, int k4shift)
{
    int t = blockIdx.x * blockDim.x + threadIdx.x;
    int K4 = 1 << k4shift;                 // K/4
    if (t >= (N << k4shift)) return;
    int i = t >> k4shift;
    int c4 = t & (K4 - 1);
    const float4* X4 = (const float4*)X;
    int s0 = starts[i], cnt = counts[i];
    float a0 = 0.f, a1 = 0.f, a2 = 0.f, a3 = 0.f;
    for (int j = s0; j < s0 + cnt; ++j) {
        float w = nrm_s[j];
        float4 h = X4[(size_t)row_s[j] * K4 + c4];
        a0 += w * h.x; a1 += w * h.y; a2 += w * h.z; a3 += w * h.w;
    }
    float di = dinv[i];
    float dd = di * di;
    float4 hs = X4[(size_t)i * K4 + c4];
    a0 += dd * hs.x; a1 += dd * hs.y; a2 += dd * hs.z; a3 += dd * hs.w;
    u16x4 o;
    o[0] = f2b(a0); o[1] = f2b(a1); o[2] = f2b(a2); o[3] = f2b(a3);
    ((u16x4*)OUT)[t] = o;
}

// ---------------- MFMA GEMM with LDS staging (no stats epilogue) ----------------
// Y[f32] = maybe_relu(A[bf16 NxK] @ W + bias). Wp is W^T [M][K] bf16.
// Block 256thr=4 waves, BM=64, BN=64(tiles of 16), BK=32. LDS stride 40 (~2-way, free).
// Fragments (gfx950 16x16x32_bf16): A row=lane&15,k=(lane>>4)*8+e ;
//   B col=lane&15,k=(lane>>4)*8+e ; D col=lane&15,row=(lane>>4)*4+reg.
__global__ __launch_bounds__(256) void k_gemm_mfma(
        const unsigned short* __restrict__ A, const unsigned short* __restrict__ Wp,
        const float* __restrict__ bias, float* __restrict__ Y,
        int N, int K, int M, int relu)
{
    __shared__ unsigned short As[64][40];
    __shared__ unsigned short Bs[64][40];

    int tid = threadIdx.x;
    int wv = tid >> 6;
    int l = tid & 63;
    int lr = l & 15;
    int lk = l >> 4;
    int brow = blockIdx.x * 64;
    int bcol = blockIdx.y * 64;
    int nct = (M - bcol) >> 4; if (nct > 4) nct = 4;

    int sr = tid >> 2;             // staging row 0..63
    int sc = (tid & 3) * 8;        // staging col {0,8,16,24}
    int gr_s = brow + sr;
    int gj_s = bcol + sr;

    f32x4 acc[4] = {};

    for (int k0 = 0; k0 < K; k0 += 32) {
        bf16x8 va = {};
        if (gr_s < N) va = *(const bf16x8*)(A + (size_t)gr_s * K + k0 + sc);
        *(bf16x8*)&As[sr][sc] = va;
        bf16x8 vb = {};
        if (gj_s < M) vb = *(const bf16x8*)(Wp + (size_t)gj_s * K + k0 + sc);
        *(bf16x8*)&Bs[sr][sc] = vb;
        __syncthreads();

        bf16x8 af = *(const bf16x8*)&As[wv * 16 + lr][lk * 8];
#pragma unroll
        for (int ct = 0; ct < 4; ++ct) {
            if (ct < nct) {
                bf16x8 bf = *(const bf16x8*)&Bs[ct * 16 + lr][lk * 8];
                acc[ct] = __builtin_amdgcn_mfma_f32_16x16x32_bf16(af, bf, acc[ct], 0, 0, 0);
            }
        }
        __syncthreads();
    }

    int i0 = brow + wv * 16;
#pragma unroll
    for (int ct = 0; ct < 4; ++ct) {
        if (ct >= nct) continue;
        int j = bcol + ct * 16 + lr;
        float bj = bias ? bias[j] : 0.0f;
#pragma unroll
        for (int r = 0; r < 4; ++r) {
            int gi = i0 + lk * 4 + r;
            if (gi < N) {
                float v = acc[ct][r] + bj;
                if (relu) v = fmaxf(v, 0.f);
                Y[(size_t)gi * M + j] = v;
            }
        }
    }
}

// ---------------- BN stats: column sums / sums-of-squares ----------------
__global__ void k_colsum(const float* __restrict__ Y, float* __restrict__ sums,
                         float* __restrict__ sumsq, int N, int M) {
    int f = threadIdx.x & (M - 1);      // M power of two
    int rsub = threadIdx.x / M;
    int R = blockDim.x / M;
    int rowsPerBlock = (N + gridDim.x - 1) / gridDim.x;
    int r0 = blockIdx.x * rowsPerBlock;
    int r1 = min(N, r0 + rowsPerBlock);
    float s = 0.0f, s2 = 0.0f;
    for (int i = r0 + rsub; i < r1; i += R) {
        float v = Y[(size_t)i * M + f];
        s += v;
        s2 += v * v;
    }
    atomicAdd(&sums[f], s);
    atomicAdd(&sumsq[f], s2);
}

// ---------------- BN: f32 in -> f32 XF (optional) + bf16 XB ----------------

__global__ void k_bnb(const float* __restrict__ Y, const float* __restrict__ sums,
                      const float* __restrict__ sumsq, const float* __restrict__ g,
                      const float* __restrict__ be, float* __restrict__ OF,
                      unsigned short* __restrict__ OB,
                      int N, int M, int reluAfter, int writeF) {
    int t = blockIdx.x * blockDim.x + threadIdx.x;
    int total = (N * M) >> 2;
    if (t >= total) return;
    int f4 = t << 2;
    int i = f4 / M;
    int f = f4 - i * M;
    (void)i;
    float invN = 1.0f / 50000.0f;
    float4 y = *(const float4*)(Y + f4);
    float4 vf;
    u16x4 ob;
#pragma unroll
    for (int j = 0; j < 4; ++j) {
        float mean = sums[f + j] * invN;
        float var = sumsq[f + j] * invN - mean * mean;
        float v = g[f + j] * (((const float*)&y)[j] - mean) * rsqrtf(var + EPS) + be[f + j];
        if (reluAfter) v = fmaxf(v, 0.f);
        ((float*)&vf)[j] = v;
        ob[j] = f2b(v);
    }
    if (writeF) *(float4*)(OF + f4) = vf;
    *(u16x4*)(OB + f4) = ob;
}

// out[i] = b2 + sum_k T[i,k] * W2[k]   (T f32)
__global__ void k_fc2(const float* __restrict__ T, const float* __restrict__ W2,
                      const float* __restrict__ b2, float* __restrict__ out,
                      int N, int K) {
    int i = blockIdx.x * blockDim.x + threadIdx.x;
    if (i >= N) return;
    const float* tr = T + (size_t)i * K;
    float acc = b2[0];
#pragma unroll 4
    for (int k = 0; k < K; ++k) acc += tr[k] * W2[k];
    out[i] = acc;
}

// ---------------- host ----------------

static inline size_t align256(size_t x) { return (x + 255) & ~(size_t)255; }

extern "C" void kernel_launch(void* const* d_in, const int* in_sizes, int n_in,
                              void* d_out, int out_size, void* d_ws, size_t ws_size,
                              hipStream_t stream) {
    const int F_IN = 32;
    const int N = in_sizes[0] / F_IN;   // 50000
    const int E = in_sizes[2];          // 400000

    const float* x  = (const float*)d_in[0];
    const int*   ei = (const int*)d_in[1];
    const float* ea = (const float*)d_in[2];
    const int* row = ei;
    const int* col = ei + E;

    const float* W[5]; const float* b[5]; const float* g[5]; const float* be[5];
    for (int i = 0; i < 5; ++i) {
        W[i]  = (const float*)d_in[3 + 4 * i + 0];
        b[i]  = (const float*)d_in[3 + 4 * i + 1];
        g[i]  = (const float*)d_in[3 + 4 * i + 2];
        be[i] = (const float*)d_in[3 + 4 * i + 3];
    }
    const float* fcW1 = (const float*)d_in[23];
    const float* fcb1 = (const float*)d_in[24];
    const float* fcW2 = (const float*)d_in[25];
    const float* fcb2 = (const float*)d_in[26];

    // workspace layout
    char* ws = (char*)d_ws;
    size_t off = 0;
    float* XF = (float*)(ws + off); off += align256((size_t)N * 128 * 4);           // f32 BN out (layers 1-4)
    unsigned short* XB = (unsigned short*)(ws + off); off += align256((size_t)N * 256 * 2); // bf16 BN out (FC1 input)
    unsigned short* CB = (unsigned short*)(ws + off); off += align256((size_t)N * 128 * 2); // bf16 gathered (GEMM A)
    float* Yf   = (float*)(ws + off); off += align256((size_t)N * 256 * 4);         // f32 GEMM out
    float* deg  = (float*)(ws + off); off += align256((size_t)N * 4);
    float* dinv = (float*)(ws + off); off += align256((size_t)N * 4);
    int* counts = (int*)(ws + off); off += align256((size_t)N * 4);
    int* starts = (int*)(ws + off); off += align256((size_t)N * 4);
    int* cursor = (int*)(ws + off); off += align256((size_t)N * 4);
    int* row_s  = (int*)(ws + off); off += align256((size_t)E * 4);
    float* nrm_s = (float*)(ws + off); off += align256((size_t)E * 4);
    float* sums  = (float*)(ws + off); off += align256(512 * 4);
    float* sumsq = sums + 256;
    const int KW[6] = {32, 32, 64, 128, 128, 256};
    const int MW[6] = {32, 64, 128, 128, 256, 128};
    unsigned short* Wp[6];
    for (int i = 0; i < 6; ++i) { Wp[i] = (unsigned short*)(ws + off); off += align256((size_t)KW[i] * MW[i] * 2); }
    (void)ws_size;

    const int BS = 256;
    auto grid1 = [&](long long total) { return (int)((total + BS - 1) / BS); };

    // --- CSR build ---
    hipMemsetAsync(deg, 0, (size_t)N * 4, stream);
    hipMemsetAsync(counts, 0, (size_t)N * 4, stream);
    hipMemsetAsync(cursor, 0, (size_t)N * 4, stream);
    k_cnt<<<grid1(E), BS, 0, stream>>>(col, ea, counts, deg, E);
    k_dinv<<<grid1(N), BS, 0, stream>>>(deg, dinv, N);
    k_scan<<<1, 1024, 0, stream>>>(counts, starts, N);
    k_fill<<<grid1(E), BS, 0, stream>>>(row, col, ea, dinv, starts, cursor, row_s, nrm_s, E);

    // --- weight packing (transpose + bf16) ---
    const float* Wsrc[6] = {W[0], W[1], W[2], W[3], W[4], fcW1};
    for (int i = 0; i < 6; ++i)
        k_packWT<<<grid1((long long)KW[i] * MW[i]), BS, 0, stream>>>(Wsrc[i], Wp[i], KW[i], MW[i]);

    auto gemm = [&](const unsigned short* Ab, int l, const float* bias, float* Y, int relu) {
        dim3 grid((N + 63) / 64, (MW[l] + 63) / 64);
        k_gemm_mfma<<<grid, 256, 0, stream>>>(Ab, Wp[l], bias, Y, N, KW[l], MW[l], relu);
    };

    // --- GCN layer: gather(f32)->CB(bf16) ; mfma-gemm->Yf ; colsum ; bn->XF/XB ---
    auto layer = [&](const float* Xin, int l, int reluBefore, int reluAfter) {
        int K = KW[l], M = MW[l];
        int k4shift = (K == 32) ? 3 : (K == 64) ? 4 : 5;
        k_gather4b<<<grid1((long long)N << k4shift), BS, 0, stream>>>(
            starts, counts, row_s, nrm_s, Xin, dinv, CB, N, k4shift);
        gemm(CB, l, b[l], Yf, reluBefore);
        hipMemsetAsync(sums, 0, 512 * 4, stream);
        k_colsum<<<256, BS, 0, stream>>>(Yf, sums, sumsq, N, M);
        k_bnb<<<grid1((long long)N * M / 4), BS, 0, stream>>>(
            Yf, sums, sumsq, g[l], be[l], XF, XB, N, M, reluAfter, M <= 128 ? 1 : 0);
    };

    layer(x,  0, 1, 0);   // 32 -> 32
    layer(XF, 1, 1, 0);   // 32 -> 64
    layer(XF, 2, 1, 0);   // 64 -> 128
    layer(XF, 3, 0, 1);   // 128 -> 128
    layer(XF, 4, 0, 1);   // 128 -> 256 (bf16 only)

    // FC1: XB(bf16 Nx256) @ fcW1 + b, ReLU -> Yf (f32 Nx128)
    gemm(XB, 5, fcb1, Yf, 1);
    // FC2
    k_fc2<<<grid1(N), BS, 0, stream>>>(Yf, fcW2, fcb2, (float*)d_out, N, 128);
}

// Round 13
// 679.535 us; speedup vs baseline: 1.4666x; 1.1153x over previous
//
#include <hip/hip_runtime.h>

#define EPS 1e-5f

typedef __attribute__((ext_vector_type(8))) short bf16x8;
typedef __attribute__((ext_vector_type(4))) float f32x4;
typedef __attribute__((ext_vector_type(4))) unsigned short u16x4;

__device__ __forceinline__ unsigned short f2b(float f) {   // f32 -> bf16 RNE
    unsigned u = __float_as_uint(f);
    unsigned r = (u + 0x7fffu + ((u >> 16) & 1u)) >> 16;
    return (unsigned short)r;
}

// ---------------- graph preprocessing ----------------

__global__ void k_cnt(const int* __restrict__ col, const float* __restrict__ w,
                      int* __restrict__ counts, float* __restrict__ deg, int E) {
    int e = blockIdx.x * blockDim.x + threadIdx.x;
    if (e < E) {
        int c = col[e];
        atomicAdd(&counts[c], 1);
        atomicAdd(&deg[c], w[e]);
    }
}

__global__ void k_dinv(const float* __restrict__ deg, float* __restrict__ dinv, int N) {
    int i = blockIdx.x * blockDim.x + threadIdx.x;
    if (i < N) dinv[i] = rsqrtf(deg[i] + 1.0f);
}

// ---- 3-stage exclusive scan of counts -> starts ----
__global__ __launch_bounds__(256) void k_scanA(const int* __restrict__ counts,
                                               int* __restrict__ starts,
                                               int* __restrict__ bsum, int N) {
    __shared__ int part[256];
    int tid = threadIdx.x;
    int t = blockIdx.x * 256 + tid;
    int v = (t < N) ? counts[t] : 0;
    part[tid] = v;
    __syncthreads();
#pragma unroll
    for (int d = 1; d < 256; d <<= 1) {
        int tmp = (tid >= d) ? part[tid - d] : 0;
        __syncthreads();
        part[tid] += tmp;
        __syncthreads();
    }
    if (t < N) starts[t] = part[tid] - v;      // local exclusive
    if (tid == 255) bsum[blockIdx.x] = part[255];
}

__global__ __launch_bounds__(256) void k_scanB(const int* __restrict__ bsum,
                                               int* __restrict__ boff, int nb) {
    __shared__ int part[256];
    int tid = threadIdx.x;
    int v = (tid < nb) ? bsum[tid] : 0;
    part[tid] = v;
    __syncthreads();
#pragma unroll
    for (int d = 1; d < 256; d <<= 1) {
        int tmp = (tid >= d) ? part[tid - d] : 0;
        __syncthreads();
        part[tid] += tmp;
        __syncthreads();
    }
    if (tid < nb) boff[tid] = part[tid] - v;   // exclusive
}

__global__ __launch_bounds__(256) void k_scanC(int* __restrict__ starts,
                                               const int* __restrict__ boff, int N) {
    int t = blockIdx.x * 256 + threadIdx.x;
    if (t < N) starts[t] += boff[blockIdx.x];
}

__global__ void k_fill(const int* __restrict__ row, const int* __restrict__ col,
                       const float* __restrict__ w, const float* __restrict__ dinv,
                       const int* __restrict__ starts, int* __restrict__ cursor,
                       int* __restrict__ row_s, float* __restrict__ nrm_s, int E) {
    int e = blockIdx.x * blockDim.x + threadIdx.x;
    if (e >= E) return;
    int c = col[e];
    int r = row[e];
    int j = starts[c] + atomicAdd(&cursor[c], 1);
    row_s[j] = r;
    nrm_s[j] = dinv[r] * w[e] * dinv[c];
}

// ---------------- weight pack: W [K][M] f32 -> Wp [M][K] bf16 (transposed) ----------------
__global__ void k_packWT(const float* __restrict__ W, unsigned short* __restrict__ Wp,
                         int K, int M) {
    int t = blockIdx.x * blockDim.x + threadIdx.x;
    if (t >= K * M) return;
    int k = t / M, j = t - k * M;
    Wp[(size_t)j * K + k] = f2b(W[t]);
}

// ---------------- BN params: scale/shift from col stats ----------------
__global__ void k_bnparam(const float* __restrict__ sums, const float* __restrict__ sumsq,
                          const float* __restrict__ g, const float* __restrict__ be,
                          float* __restrict__ scale, float* __restrict__ shift, int M) {
    int f = threadIdx.x;
    if (f >= M) return;
    float invN = 1.0f / 50000.0f;
    float mean = sums[f] * invN;
    float var = sumsq[f] * invN - mean * mean;
    float s = g[f] * rsqrtf(var + EPS);
    scale[f] = s;
    shift[f] = be[f] - mean * s;
}

// ---------------- aggregation (CSR gather, f32 in + optional inline BN, bf16 out) ----------------
// xv = relu?( X[r,c]*scale[c]+shift[c] ) ; OUT[i,c] = bf16( sum_j nrm*xv_j + dinv^2*xv_i )
__global__ __launch_bounds__(256) void k_gather4s(
        const int* __restrict__ starts, const int* __restrict__ counts,
        const int* __restrict__ row_s, const float* __restrict__ nrm_s,
        const float* __restrict__ X, const float* __restrict__ dinv,
        const float* __restrict__ scale, const float* __restrict__ shift,
        unsigned short* __restrict__ OUT, int N, int k4shift, int applyRelu)
{
    int t = blockIdx.x * blockDim.x + threadIdx.x;
    int K4 = 1 << k4shift;                 // K/4
    if (t >= (N << k4shift)) return;
    int i = t >> k4shift;
    int c4 = t & (K4 - 1);
    const float4* X4 = (const float4*)X;
    float4 sc = make_float4(1.f, 1.f, 1.f, 1.f);
    float4 sh = make_float4(0.f, 0.f, 0.f, 0.f);
    if (scale) {
        sc = *(const float4*)(scale + c4 * 4);
        sh = *(const float4*)(shift + c4 * 4);
    }
    int s0 = starts[i], cnt = counts[i];
    float a0 = 0.f, a1 = 0.f, a2 = 0.f, a3 = 0.f;
    for (int j = s0; j < s0 + cnt; ++j) {
        float w = nrm_s[j];
        float4 h = X4[(size_t)row_s[j] * K4 + c4];
        float h0 = h.x * sc.x + sh.x, h1 = h.y * sc.y + sh.y;
        float h2 = h.z * sc.z + sh.z, h3 = h.w * sc.w + sh.w;
        if (applyRelu) {
            h0 = fmaxf(h0, 0.f); h1 = fmaxf(h1, 0.f);
            h2 = fmaxf(h2, 0.f); h3 = fmaxf(h3, 0.f);
        }
        a0 += w * h0; a1 += w * h1; a2 += w * h2; a3 += w * h3;
    }
    float di = dinv[i];
    float dd = di * di;
    float4 h = X4[(size_t)i * K4 + c4];
    float h0 = h.x * sc.x + sh.x, h1 = h.y * sc.y + sh.y;
    float h2 = h.z * sc.z + sh.z, h3 = h.w * sc.w + sh.w;
    if (applyRelu) {
        h0 = fmaxf(h0, 0.f); h1 = fmaxf(h1, 0.f);
        h2 = fmaxf(h2, 0.f); h3 = fmaxf(h3, 0.f);
    }
    a0 += dd * h0; a1 += dd * h1; a2 += dd * h2; a3 += dd * h3;
    u16x4 o;
    o[0] = f2b(a0); o[1] = f2b(a1); o[2] = f2b(a2); o[3] = f2b(a3);
    ((u16x4*)OUT)[t] = o;
}

// ---------------- MFMA GEMM with LDS staging ----------------
__global__ __launch_bounds__(256) void k_gemm_mfma(
        const unsigned short* __restrict__ A, const unsigned short* __restrict__ Wp,
        const float* __restrict__ bias, float* __restrict__ Y,
        int N, int K, int M, int relu)
{
    __shared__ unsigned short As[64][40];
    __shared__ unsigned short Bs[64][40];

    int tid = threadIdx.x;
    int wv = tid >> 6;
    int l = tid & 63;
    int lr = l & 15;
    int lk = l >> 4;
    int brow = blockIdx.x * 64;
    int bcol = blockIdx.y * 64;
    int nct = (M - bcol) >> 4; if (nct > 4) nct = 4;

    int sr = tid >> 2;
    int sc = (tid & 3) * 8;
    int gr_s = brow + sr;
    int gj_s = bcol + sr;

    f32x4 acc[4] = {};

    for (int k0 = 0; k0 < K; k0 += 32) {
        bf16x8 va = {};
        if (gr_s < N) va = *(const bf16x8*)(A + (size_t)gr_s * K + k0 + sc);
        *(bf16x8*)&As[sr][sc] = va;
        bf16x8 vb = {};
        if (gj_s < M) vb = *(const bf16x8*)(Wp + (size_t)gj_s * K + k0 + sc);
        *(bf16x8*)&Bs[sr][sc] = vb;
        __syncthreads();

        bf16x8 af = *(const bf16x8*)&As[wv * 16 + lr][lk * 8];
#pragma unroll
        for (int ct = 0; ct < 4; ++ct) {
            if (ct < nct) {
                bf16x8 bf = *(const bf16x8*)&Bs[ct * 16 + lr][lk * 8];
                acc[ct] = __builtin_amdgcn_mfma_f32_16x16x32_bf16(af, bf, acc[ct], 0, 0, 0);
            }
        }
        __syncthreads();
    }

    int i0 = brow + wv * 16;
#pragma unroll
    for (int ct = 0; ct < 4; ++ct) {
        if (ct >= nct) continue;
        int j = bcol + ct * 16 + lr;
        float bj = bias ? bias[j] : 0.0f;
#pragma unroll
        for (int r = 0; r < 4; ++r) {
            int gi = i0 + lk * 4 + r;
            if (gi < N) {
                float v = acc[ct][r] + bj;
                if (relu) v = fmaxf(v, 0.f);
                Y[(size_t)gi * M + j] = v;
            }
        }
    }
}

// ---------------- BN stats: column sums / sums-of-squares ----------------
__global__ void k_colsum(const float* __restrict__ Y, float* __restrict__ sums,
                         float* __restrict__ sumsq, int N, int M) {
    int f = threadIdx.x & (M - 1);
    int rsub = threadIdx.x / M;
    int R = blockDim.x / M;
    int rowsPerBlock = (N + gridDim.x - 1) / gridDim.x;
    int r0 = blockIdx.x * rowsPerBlock;
    int r1 = min(N, r0 + rowsPerBlock);
    float s = 0.0f, s2 = 0.0f;
    for (int i = r0 + rsub; i < r1; i += R) {
        float v = Y[(size_t)i * M + f];
        s += v;
        s2 += v * v;
    }
    atomicAdd(&sums[f], s);
    atomicAdd(&sumsq[f], s2);
}

// ---------------- BN apply (layer 5 only): f32 -> bf16 ----------------
__global__ void k_bnb(const float* __restrict__ Y, const float* __restrict__ sums,
                      const float* __restrict__ sumsq, const float* __restrict__ g,
                      const float* __restrict__ be, unsigned short* __restrict__ OB,
                      int N, int M, int reluAfter) {
    int t = blockIdx.x * blockDim.x + threadIdx.x;
    int total = (N * M) >> 2;
    if (t >= total) return;
    int f4 = t << 2;
    int i = f4 / M;
    int f = f4 - i * M;
    (void)i;
    float invN = 1.0f / 50000.0f;
    float4 y = *(const float4*)(Y + f4);
    u16x4 ob;
#pragma unroll
    for (int j = 0; j < 4; ++j) {
        float mean = sums[f + j] * invN;
        float var = sumsq[f + j] * invN - mean * mean;
        float v = g[f + j] * (((const float*)&y)[j] - mean) * rsqrtf(var + EPS) + be[f + j];
        if (reluAfter) v = fmaxf(v, 0.f);
        ob[j] = f2b(v);
    }
    *(u16x4*)(OB + f4) = ob;
}

// ---------------- FC2: wave-per-node, coalesced ----------------
__global__ __launch_bounds__(256) void k_fc2w(const float* __restrict__ T,
                                              const float* __restrict__ W2,
                                              const float* __restrict__ b2,
                                              float* __restrict__ out, int N) {
    int gid = blockIdx.x * 256 + threadIdx.x;
    int node = gid >> 6;
    int lane = threadIdx.x & 63;
    if (node >= N) return;
    const float* tr = T + (size_t)node * 128;
    float acc = tr[lane] * W2[lane] + tr[lane + 64] * W2[lane + 64];
#pragma unroll
    for (int d = 32; d; d >>= 1) acc += __shfl_xor(acc, d);
    if (lane == 0) out[node] = acc + b2[0];
}

// ---------------- host ----------------

static inline size_t align256(size_t x) { return (x + 255) & ~(size_t)255; }

extern "C" void kernel_launch(void* const* d_in, const int* in_sizes, int n_in,
                              void* d_out, int out_size, void* d_ws, size_t ws_size,
                              hipStream_t stream) {
    const int F_IN = 32;
    const int N = in_sizes[0] / F_IN;   // 50000
    const int E = in_sizes[2];          // 400000

    const float* x  = (const float*)d_in[0];
    const int*   ei = (const int*)d_in[1];
    const float* ea = (const float*)d_in[2];
    const int* row = ei;
    const int* col = ei + E;

    const float* W[5]; const float* b[5]; const float* g[5]; const float* be[5];
    for (int i = 0; i < 5; ++i) {
        W[i]  = (const float*)d_in[3 + 4 * i + 0];
        b[i]  = (const float*)d_in[3 + 4 * i + 1];
        g[i]  = (const float*)d_in[3 + 4 * i + 2];
        be[i] = (const float*)d_in[3 + 4 * i + 3];
    }
    const float* fcW1 = (const float*)d_in[23];
    const float* fcb1 = (const float*)d_in[24];
    const float* fcW2 = (const float*)d_in[25];
    const float* fcb2 = (const float*)d_in[26];

    // workspace
    char* ws = (char*)d_ws;
    size_t off = 0;
    unsigned short* XB = (unsigned short*)(ws + off); off += align256((size_t)N * 256 * 2); // bf16 (FC1 input)
    unsigned short* CB = (unsigned short*)(ws + off); off += align256((size_t)N * 128 * 2); // bf16 gathered
    float* Yf   = (float*)(ws + off); off += align256((size_t)N * 256 * 4);                 // f32 GEMM out
    float* deg  = (float*)(ws + off); off += align256((size_t)N * 4);
    float* dinv = (float*)(ws + off); off += align256((size_t)N * 4);
    int* counts = (int*)(ws + off); off += align256((size_t)N * 4);
    int* starts = (int*)(ws + off); off += align256((size_t)N * 4);
    int* cursor = (int*)(ws + off); off += align256((size_t)N * 4);
    int* row_s  = (int*)(ws + off); off += align256((size_t)E * 4);
    float* nrm_s = (float*)(ws + off); off += align256((size_t)E * 4);
    float* sums  = (float*)(ws + off); off += align256(512 * 4);
    float* sumsq = sums + 256;
    int* bsum = (int*)(ws + off); off += align256(256 * 4);
    int* boff = (int*)(ws + off); off += align256(256 * 4);
    float* scale = (float*)(ws + off); off += align256(256 * 4);
    float* shift = (float*)(ws + off); off += align256(256 * 4);
    const int KW[6] = {32, 32, 64, 128, 128, 256};
    const int MW[6] = {32, 64, 128, 128, 256, 128};
    unsigned short* Wp[6];
    for (int i = 0; i < 6; ++i) { Wp[i] = (unsigned short*)(ws + off); off += align256((size_t)KW[i] * MW[i] * 2); }
    (void)ws_size;

    const int BS = 256;
    auto grid1 = [&](long long total) { return (int)((total + BS - 1) / BS); };
    const int nb = (N + 255) / 256;   // scan blocks (196)

    // --- CSR build ---
    hipMemsetAsync(deg, 0, (size_t)N * 4, stream);
    hipMemsetAsync(counts, 0, (size_t)N * 4, stream);
    hipMemsetAsync(cursor, 0, (size_t)N * 4, stream);
    k_cnt<<<grid1(E), BS, 0, stream>>>(col, ea, counts, deg, E);
    k_dinv<<<grid1(N), BS, 0, stream>>>(deg, dinv, N);
    k_scanA<<<nb, 256, 0, stream>>>(counts, starts, bsum, N);
    k_scanB<<<1, 256, 0, stream>>>(bsum, boff, nb);
    k_scanC<<<nb, 256, 0, stream>>>(starts, boff, N);
    k_fill<<<grid1(E), BS, 0, stream>>>(row, col, ea, dinv, starts, cursor, row_s, nrm_s, E);

    // --- weight packing ---
    const float* Wsrc[6] = {W[0], W[1], W[2], W[3], W[4], fcW1};
    for (int i = 0; i < 6; ++i)
        k_packWT<<<grid1((long long)KW[i] * MW[i]), BS, 0, stream>>>(Wsrc[i], Wp[i], KW[i], MW[i]);

    auto gemm = [&](const unsigned short* Ab, int l, const float* bias, float* Y, int relu) {
        dim3 grid((N + 63) / 64, (MW[l] + 63) / 64);
        k_gemm_mfma<<<grid, 256, 0, stream>>>(Ab, Wp[l], bias, Y, N, KW[l], MW[l], relu);
    };

    // --- layer: gather(prev f32, inline BN) -> CB ; gemm -> Yf ; colsum ---
    // Xin: f32 source (x or Yf). bnOf: stats layer applied inline (-1 = none).
    auto layer = [&](const float* Xin, int l, int bnOf, int bnRelu, int reluBefore) {
        int K = KW[l];
        int k4shift = (K == 32) ? 3 : (K == 64) ? 4 : 5;
        if (bnOf >= 0)
            k_bnparam<<<1, 256, 0, stream>>>(sums, sumsq, g[bnOf], be[bnOf], scale, shift, MW[bnOf]);
        k_gather4s<<<grid1((long long)N << k4shift), BS, 0, stream>>>(
            starts, counts, row_s, nrm_s, Xin, dinv,
            bnOf >= 0 ? scale : nullptr, bnOf >= 0 ? shift : nullptr,
            CB, N, k4shift, bnRelu);
        gemm(CB, l, b[l], Yf, reluBefore);
        hipMemsetAsync(sums, 0, 512 * 4, stream);
        k_colsum<<<256, BS, 0, stream>>>(Yf, sums, sumsq, N, MW[l]);
    };

    layer(x,  0, -1, 0, 1);   // L1: 32 -> 32, pre-BN relu
    layer(Yf, 1, 0, 0, 1);    // L2: BN(L1) inline, no relu-after
    layer(Yf, 2, 1, 0, 1);    // L3
    layer(Yf, 3, 2, 0, 0);    // L4: no pre-relu
    layer(Yf, 4, 3, 1, 0);    // L5: BN(L4) inline WITH relu (L4 reluAfter)

    // L5 BN apply -> XB (bf16), relu
    k_bnb<<<grid1((long long)N * 256 / 4), BS, 0, stream>>>(
        Yf, sums, sumsq, g[4], be[4], XB, N, 256, 1);

    // FC1: XB(bf16 Nx256) @ fcW1 + b, ReLU -> Yf (f32 Nx128)
    gemm(XB, 5, fcb1, Yf, 1);
    // FC2: wave-per-node
    k_fc2w<<<(N * 64 + 255) / 256, 256, 0, stream>>>(Yf, fcW2, fcb2, (float*)d_out, N);
}